// Round 7
// baseline (211.534 us; speedup 1.0000x reference)
//
#include <hip/hip_runtime.h>

#define N_TRAIN 100000
#define N_DIM   256
#define BATCH   16384

// out[i,j] = order[ clip(floor(Phi(noise[i,j]) * N_TRAIN), 0, N_TRAIN-1), j ]
// noise: [BATCH, N_DIM] f32, order: [N_TRAIN, N_DIM] f32 (sorted per column)
//
// Thread t handles 4 consecutive elements of the row-major [BATCH, N_DIM]
// arrays -> noise load + out store fully coalesced (16B/lane).
// noise/out are streaming (touched once) -> non-temporal, so they don't
// evict the reused order table from L2. The gather order[idx*256+j] is
// inherently scattered (random row per lane) but the 102.4 MB table is
// L3-resident, so these are mostly L2/L3 hits.

typedef float vfloat4 __attribute__((ext_vector_type(4)));

__global__ __launch_bounds__(256) void icdf_gather_kernel(
    const float* __restrict__ noise,
    const float* __restrict__ order,
    float* __restrict__ out)
{
    const int t = blockIdx.x * blockDim.x + threadIdx.x;
    const int e = t * 4;                       // first element index
    if (e >= BATCH * N_DIM) return;

    const vfloat4 nv = __builtin_nontemporal_load(
        reinterpret_cast<const vfloat4*>(noise + e));
    const int j = e & (N_DIM - 1);             // column of element 0 (j..j+3 same row)

    const float kInvSqrt2 = 0.70710678118654752440f;
    const float kN = (float)N_TRAIN;

    // Phi(x) = 0.5 * erfc(-x / sqrt(2))  (matches jax.scipy.special.ndtr in f32)
    float u0 = 0.5f * erfcf(-nv.x * kInvSqrt2);
    float u1 = 0.5f * erfcf(-nv.y * kInvSqrt2);
    float u2 = 0.5f * erfcf(-nv.z * kInvSqrt2);
    float u3 = 0.5f * erfcf(-nv.w * kInvSqrt2);

    int i0 = (int)floorf(u0 * kN);
    int i1 = (int)floorf(u1 * kN);
    int i2 = (int)floorf(u2 * kN);
    int i3 = (int)floorf(u3 * kN);

    i0 = min(max(i0, 0), N_TRAIN - 1);
    i1 = min(max(i1, 0), N_TRAIN - 1);
    i2 = min(max(i2, 0), N_TRAIN - 1);
    i3 = min(max(i3, 0), N_TRAIN - 1);

    // Separate address formation from use so all 4 gathers issue back-to-back.
    const float* p0 = order + (size_t)i0 * N_DIM + (j + 0);
    const float* p1 = order + (size_t)i1 * N_DIM + (j + 1);
    const float* p2 = order + (size_t)i2 * N_DIM + (j + 2);
    const float* p3 = order + (size_t)i3 * N_DIM + (j + 3);

    vfloat4 o;
    o.x = *p0;
    o.y = *p1;
    o.z = *p2;
    o.w = *p3;

    __builtin_nontemporal_store(o, reinterpret_cast<vfloat4*>(out + e));
}

extern "C" void kernel_launch(void* const* d_in, const int* in_sizes, int n_in,
                              void* d_out, int out_size, void* d_ws, size_t ws_size,
                              hipStream_t stream)
{
    const float* noise = (const float*)d_in[0];
    const float* order = (const float*)d_in[1];
    float* out = (float*)d_out;

    const int total = BATCH * N_DIM;           // 4,194,304 elements
    const int threads = total / 4;             // 1,048,576 threads (4 elems each)
    const int block = 256;
    const int grid = threads / block;          // 4096 blocks

    icdf_gather_kernel<<<grid, block, 0, stream>>>(noise, order, out);
}

// Round 14
// 194.234 us; speedup vs baseline: 1.0891x; 1.0891x over previous
//
#include <hip/hip_runtime.h>

#define N_TRAIN 100000
#define N_DIM   256
#define BATCH   16384
#define QUARTER 25000

// out[i,j] = order[ clip(floor(Phi(noise[i,j]) * N_TRAIN), 0, N_TRAIN-1), j ]
//
// Structure: 16-col stripe (= one 64B line of `order`) x XCD affinity,
// PLUS index-range quartering: gathers execute in 4 passes by quantile-row
// quarter (idx/25000), so each pass's unique-line working set (~1.5 MB)
// fits one XCD's 4 MB L2 with margin -> near-full intra-stripe line reuse.
//
// Geometry: 16 stripes x 64 chunks (256 rows) = 1024 blocks, 256 threads.
// bid%8 == stripe%8 -> all chunks of a stripe land on one XCD (round-robin
// dispatch heuristic; perf-only). Thread covers 4 cols x 4 row-steps = 16
// elements: compute all u/idx once into registers, gather per quarter pass,
// buffer results in registers, one float4 NT store per row-step at the end.
// noise/out accesses are 16B/lane coalesced + non-temporal (don't evict the
// stripe lines from L2).

typedef float vfloat4 __attribute__((ext_vector_type(4)));

__global__ __launch_bounds__(256) void icdf_stripe_q_kernel(
    const float* __restrict__ noise,
    const float* __restrict__ order,
    float* __restrict__ out)
{
    const int bid = blockIdx.x;
    const int stripe = ((bid >> 9) << 3) | (bid & 7);   // 0..15
    const int chunk  = (bid & 511) >> 3;                // 0..63
    const int j0 = stripe * 16;
    const int i0 = chunk * 256;

    const int lane_col = (threadIdx.x & 3) * 4;         // 0,4,8,12
    const int row_off  = threadIdx.x >> 2;              // 0..63
    const int jbase = j0 + lane_col;

    const float kInvSqrt2 = 0.70710678118654752440f;
    const float kN = (float)N_TRAIN;

    int   idxs[4][4];
    float res [4][4];
    size_t ebase[4];

    // ---- compute phase: all 16 indices into registers ----
    #pragma unroll
    for (int p = 0; p < 4; ++p) {
        const int i = i0 + row_off + (p << 6);
        const size_t e = (size_t)i * N_DIM + jbase;
        ebase[p] = e;

        const vfloat4 nv = __builtin_nontemporal_load(
            reinterpret_cast<const vfloat4*>(noise + e));

        float u0 = 0.5f * erfcf(-nv.x * kInvSqrt2);
        float u1 = 0.5f * erfcf(-nv.y * kInvSqrt2);
        float u2 = 0.5f * erfcf(-nv.z * kInvSqrt2);
        float u3 = 0.5f * erfcf(-nv.w * kInvSqrt2);

        int a = (int)floorf(u0 * kN);
        int b = (int)floorf(u1 * kN);
        int c = (int)floorf(u2 * kN);
        int d = (int)floorf(u3 * kN);

        idxs[p][0] = min(max(a, 0), N_TRAIN - 1);
        idxs[p][1] = min(max(b, 0), N_TRAIN - 1);
        idxs[p][2] = min(max(c, 0), N_TRAIN - 1);
        idxs[p][3] = min(max(d, 0), N_TRAIN - 1);
    }

    // ---- gather passes: one quantile-row quarter at a time ----
    #pragma unroll
    for (int q = 0; q < 4; ++q) {
        const int lo = q * QUARTER;
        const int hi = lo + QUARTER;   // last quarter: 100000 covers idx<=99999
        __syncthreads();               // bound intra-block pass drift
        #pragma unroll
        for (int p = 0; p < 4; ++p) {
            #pragma unroll
            for (int k = 0; k < 4; ++k) {
                const int ix = idxs[p][k];
                if (ix >= lo && ix < hi) {
                    res[p][k] = order[(size_t)ix * N_DIM + (jbase + k)];
                }
            }
        }
    }

    // ---- store phase: full float4 NT stores ----
    #pragma unroll
    for (int p = 0; p < 4; ++p) {
        vfloat4 o;
        o.x = res[p][0];
        o.y = res[p][1];
        o.z = res[p][2];
        o.w = res[p][3];
        __builtin_nontemporal_store(o, reinterpret_cast<vfloat4*>(out + ebase[p]));
    }
}

extern "C" void kernel_launch(void* const* d_in, const int* in_sizes, int n_in,
                              void* d_out, int out_size, void* d_ws, size_t ws_size,
                              hipStream_t stream)
{
    const float* noise = (const float*)d_in[0];
    const float* order = (const float*)d_in[1];
    float* out = (float*)d_out;

    // 16 stripes x 64 chunks = 1024 blocks
    icdf_stripe_q_kernel<<<1024, 256, 0, stream>>>(noise, order, out);
}